// Round 16
// baseline (4772.232 us; speedup 1.0000x reference)
//
#include <hip/hip_runtime.h>
#include <hip/hip_bf16.h>

// Problem constants
#define BB 32     // batch
#define TT 512    // time
#define AA 512    // acoustic dim
#define EE 256    // emb dim
#define HH 320    // hidden
#define VV 8192   // vocab
#define KIN 768   // A+E
#define G4 1280   // 4*H

#define NBLK 8    // recurrence blocks (one sync group)
#define UPB 40    // hidden units per block
#define RTHR 640  // threads (10 waves)

#define POISON 0x7F7F7F7F7F7F7F7FULL   // 4x bf16 0x7F7F — unreachable for h in [-1,1]

typedef __bf16 bf16x8v __attribute__((ext_vector_type(8)));
typedef float f32x4 __attribute__((ext_vector_type(4)));
typedef unsigned long long u64;

__device__ __forceinline__ float fsigm(float x) { return 1.f / (1.f + __expf(-x)); }
__device__ __forceinline__ float ftanh(float x) { return 2.f / (1.f + __expf(-2.f * x)) - 1.f; }
__device__ __forceinline__ unsigned short f2bf(float f) {
    __hip_bfloat16 h = __float2bfloat16(f);
    return *(unsigned short*)&h;
}
// any 16-bit lane of y equal to zero?
__device__ __forceinline__ u64 zero16(u64 y) {
    return (y - 0x0001000100010001ULL) & ~y & 0x8000800080008000ULL;
}
// runtime-index select from f32x4 (cndmask chain, no scratch)
__device__ __forceinline__ float pick4(f32x4 v, int i) {
    const float ab = (i & 1) ? v[1] : v[0];
    const float cd = (i & 1) ? v[3] : v[2];
    return (i & 2) ? cd : ab;
}
__device__ __forceinline__ float sel4(float a, float b, float c, float d, int i) {
    const float ab = (i & 1) ? b : a;
    const float cd = (i & 1) ? d : c;
    return (i & 2) ? cd : ab;
}

// ---------------- Stage A: X[r=t*B+b][j] = tanh(concat(a,e) . W_in[j,:] + b_in[j]) ----------------
__global__ __launch_bounds__(320) void stage_x(const float* __restrict__ ac,
                                               const int* __restrict__ tok,
                                               const float* __restrict__ emb,
                                               const float* __restrict__ Win,
                                               const float* __restrict__ bin,
                                               float* __restrict__ X) {
    __shared__ float xs[8][KIN];
    const int r0 = blockIdx.x * 8;
    const int tid = threadIdx.x;
    for (int rr = 0; rr < 8; ++rr) {
        const int r = r0 + rr;
        const int t = r >> 5;
        const int b = r & 31;
        const int tk = tok[b * TT + t];
        const float4* ac4  = (const float4*)(ac + ((size_t)b * TT + t) * AA);
        const float4* emb4 = (const float4*)(emb + (size_t)tk * EE);
        float4* xs4 = (float4*)&xs[rr][0];
        for (int k4 = tid; k4 < KIN / 4; k4 += 320) {
            float4 v;
            if (k4 < AA / 4) v = ac4[k4];
            else if (tk == 0) v = make_float4(0.f, 0.f, 0.f, 0.f);
            else v = emb4[k4 - AA / 4];
            xs4[k4] = v;
        }
    }
    __syncthreads();
    const int j = tid;
    float acc[8];
    const float bj = bin[j];
#pragma unroll
    for (int rr = 0; rr < 8; ++rr) acc[rr] = bj;
    const float4* w4 = (const float4*)(Win + (size_t)j * KIN);
#pragma unroll 4
    for (int k4 = 0; k4 < KIN / 4; ++k4) {
        const float4 wv = w4[k4];
#pragma unroll
        for (int rr = 0; rr < 8; ++rr) {
            const float4 xv = ((const float4*)&xs[rr][0])[k4];
            acc[rr] += wv.x * xv.x + wv.y * xv.y + wv.z * xv.z + wv.w * xv.w;
        }
    }
#pragma unroll
    for (int rr = 0; rr < 8; ++rr)
        X[(size_t)(r0 + rr) * HH + j] = tanhf(acc[rr]);
}

// ---------------- Stage B: Gp layout [t][p][row'(160)=lu*4+q][b(32)] ----------------
__global__ __launch_bounds__(256) void stage_gin(const float* __restrict__ X,
                                                 const float* __restrict__ Wih,
                                                 const float* __restrict__ bih,
                                                 const float* __restrict__ bhh,
                                                 float* __restrict__ Gp) {
    __shared__ float xs[8][HH];
    const int r0 = blockIdx.x * 8;
    const int tid = threadIdx.x;
    {
        const float4* src = (const float4*)(X + (size_t)r0 * HH);
        float4* dst = (float4*)&xs[0][0];
        for (int k4 = tid; k4 < 8 * HH / 4; k4 += 256) dst[k4] = src[k4];
    }
    __syncthreads();
    const int t = r0 >> 5;
    const int b0 = r0 & 31;
    for (int p5 = 0; p5 < 5; ++p5) {
        const int j = tid + 256 * p5;   // 0..1279
        const float bias = bih[j] + bhh[j];
        float acc[8];
#pragma unroll
        for (int rr = 0; rr < 8; ++rr) acc[rr] = bias;
        const float4* w4 = (const float4*)(Wih + (size_t)j * HH);
#pragma unroll 4
        for (int k4 = 0; k4 < HH / 4; ++k4) {
            const float4 wv = w4[k4];
#pragma unroll
            for (int rr = 0; rr < 8; ++rr) {
                const float4 xv = ((const float4*)&xs[rr][0])[k4];
                acc[rr] += wv.x * xv.x + wv.y * xv.y + wv.z * xv.z + wv.w * xv.w;
            }
        }
        const int q = j / HH;            // gate 0..3
        const int hi = j - q * HH;       // hidden idx 0..319
        const int pp = hi / UPB;         // slice
        const int lu = hi - pp * UPB;    // local unit
        const int rowp = lu * 4 + q;     // row' within slice panel
        float* dst = Gp + (((size_t)t * NBLK + pp) * 160 + rowp) * 32 + b0;
#pragma unroll
        for (int rr = 0; rr < 8; ++rr) dst[rr] = acc[rr];
    }
}

// ---------------- Wout fp32 -> bf16 ----------------
__global__ __launch_bounds__(256) void wcvt(const float* __restrict__ src,
                                            unsigned short* __restrict__ dst, int n4) {
    const int i = blockIdx.x * 256 + threadIdx.x;
    if (i < n4) {
        const float4 v = ((const float4*)src)[i];
        ushort4 o;
        o.x = f2bf(v.x); o.y = f2bf(v.y); o.z = f2bf(v.z); o.w = f2bf(v.w);
        ((ushort4*)dst)[i] = o;
    }
}

// ---------------- Whh -> bf16, frag layout [p(8)][tile(10)][kc(10)][lane(64)][8] ----------------
// tile row sr = tw*16 + (lane&15) encodes row' = lu*4 + q => lu = sr>>2, q = sr&3;
// global Whh row = q*320 + p*40 + lu; k = kc*32 + (lane>>4)*8 + e
__global__ __launch_bounds__(256) void wcvt_whh(const float* __restrict__ Whh,
                                                unsigned short* __restrict__ dst) {
    const int i = blockIdx.x * 256 + threadIdx.x;   // 0 .. 8*10*10*64-1
    if (i >= NBLK * 10 * 10 * 64) return;
    const int l = i & 63;
    const int kc = (i >> 6) % 10;
    const int tw = (i / 640) % 10;
    const int p = i / 6400;
    const int sr = tw * 16 + (l & 15);
    const int lu = sr >> 2, q = sr & 3;
    const int grow = q * HH + p * UPB + lu;
    const int k0 = kc * 32 + (l >> 4) * 8;
    const float* s = Whh + (size_t)grow * HH + k0;
    const float4 v0 = *(const float4*)s;
    const float4 v1 = *(const float4*)(s + 4);
    unsigned short tmp[8] = { f2bf(v0.x), f2bf(v0.y), f2bf(v0.z), f2bf(v0.w),
                              f2bf(v1.x), f2bf(v1.y), f2bf(v1.z), f2bf(v1.w) };
    *(uint4*)(dst + (size_t)i * 8) = *(const uint4*)tmp;
}

// ---------------- Stage C: MFMA recurrence, 8 blocks, 1 barrier/step, shfl-cell ----------------
// Block p owns units [p*40,p*40+40) for ALL 32 batches. Wave w = n-tile w (rows' 16w..16w+15,
// i.e. units 4w..4w+3 x gates 0..3). Lane (lr,lk): gate q=lr&3, unit lu=4w+(lr>>2),
// batches lk*4+q (+16). Quad-buffered poison-poll handoff (r15-proven). Hl double-buffered
// => staging(t+1) never WARs MFMA(t) => ONE __syncthreads per step. Cell gates gathered
// via shfl_xor(1,2,3) within the 4-lane gate group; h packed via shfl_xor(4,8) to 8B stores.
__global__ __launch_bounds__(RTHR) void stage_rec(const float* __restrict__ Gp,
                                                  const unsigned short* __restrict__ Whhp,
                                                  unsigned short* __restrict__ Hsb,
                                                  unsigned short* __restrict__ hb) { // [4][BB][HH]
    const int p = blockIdx.x;             // 0..7
    const int tid = threadIdx.x;
    const int l = tid & 63, w = tid >> 6; // wave = n-tile 0..9
    const int lr = l & 15, lk = l >> 4;
    const int q = lr & 3;                 // gate index
    const int a = lr >> 2;                // unit-within-tile 0..3

    __shared__ unsigned short Hl[2][32][328]; // double-buffered staged h (42 KB)

    // ---- B fragments: 10 per lane (one n-tile per wave), pre-converted bf16 ----
    bf16x8v bfr[10];
#pragma unroll
    for (int kc = 0; kc < 10; ++kc)
        bfr[kc] = *(const bf16x8v*)(Whhp + ((size_t)((p * 10 + w) * 10 + kc) * 64 + l) * 8);

    float c0 = 0.f, c1 = 0.f;             // cells (unit lu, batch lk*4+q) and (+16)

    // staging ownership: thread owns one 32B chunk: row sm, shorts [sk, sk+16)
    const int sm = tid / 20;              // 0..31
    const int sk = (tid - sm * 20) * 16;  // 0,16,...,304

    for (int t = 0; t < TT; ++t) {
        // gate-input loads (issued before the poll; consumed after barrier)
        const float* gp = Gp + (((size_t)t * NBLK + p) * 160 + 16 * w + lr) * 32;
        const float4 ga = *(const float4*)(gp + lk * 4);
        const float4 gb = *(const float4*)(gp + 16 + lk * 4);

        if (t > 0) {
            // ---- cooperative poison-poll of slot (t-1)&3 into Hl[t&1] ----
            const int slot = (t - 1) & 3;
            const u64* src = (const u64*)(hb + ((size_t)slot * BB + sm) * HH + sk);
            u64 v0, v1, v2, v3;
            for (;;) {
                v0 = __hip_atomic_load(src + 0, __ATOMIC_RELAXED, __HIP_MEMORY_SCOPE_AGENT);
                v1 = __hip_atomic_load(src + 1, __ATOMIC_RELAXED, __HIP_MEMORY_SCOPE_AGENT);
                v2 = __hip_atomic_load(src + 2, __ATOMIC_RELAXED, __HIP_MEMORY_SCOPE_AGENT);
                v3 = __hip_atomic_load(src + 3, __ATOMIC_RELAXED, __HIP_MEMORY_SCOPE_AGENT);
                const u64 bad = zero16(v0 ^ POISON) | zero16(v1 ^ POISON) |
                                zero16(v2 ^ POISON) | zero16(v3 ^ POISON);
                if (bad == 0) break;
            }
            u64* d = (u64*)&Hl[t & 1][sm][sk];
            d[0] = v0; d[1] = v1; d[2] = v2; d[3] = v3;
        }
        __syncthreads();   // bar0: Hl[t&1] staged; all MFMA(t-1) reads long done (see note)

        f32x4 acc0 = {}, acc1 = {};
        if (t > 0) {
#pragma unroll
            for (int kc = 0; kc < 10; ++kc) {
                const bf16x8v av0 = *(const bf16x8v*)&Hl[t & 1][lr][kc * 32 + lk * 8];
                const bf16x8v av1 = *(const bf16x8v*)&Hl[t & 1][16 + lr][kc * 32 + lk * 8];
                acc0 = __builtin_amdgcn_mfma_f32_16x16x32_bf16(av0, bfr[kc], acc0, 0, 0, 0);
                acc1 = __builtin_amdgcn_mfma_f32_16x16x32_bf16(av1, bfr[kc], acc1, 0, 0, 0);
            }
        }
        // totals = MFMA + gate inputs (batch = lk*4+rg; gate row' = 16w+lr)
        f32x4 tot0 = acc0, tot1 = acc1;
        tot0[0] += ga.x; tot0[1] += ga.y; tot0[2] += ga.z; tot0[3] += ga.w;
        tot1[0] += gb.x; tot1[1] += gb.y; tot1[2] += gb.z; tot1[3] += gb.w;

        // gather the 4 gates of my cell (batch lk*4+q) from the 4-lane gate group
        const float s00 = pick4(tot0, q);
        const float s01 = __shfl_xor(pick4(tot0, q ^ 1), 1, 64);
        const float s02 = __shfl_xor(pick4(tot0, q ^ 2), 2, 64);
        const float s03 = __shfl_xor(pick4(tot0, q ^ 3), 3, 64);
        const float s10 = pick4(tot1, q);
        const float s11 = __shfl_xor(pick4(tot1, q ^ 1), 1, 64);
        const float s12 = __shfl_xor(pick4(tot1, q ^ 2), 2, 64);
        const float s13 = __shfl_xor(pick4(tot1, q ^ 3), 3, 64);
        // gate[j] = s_{j^q}
        const float gi0 = sel4(s00, s01, s02, s03, q);
        const float gf0 = sel4(s00, s01, s02, s03, q ^ 1);
        const float gg0 = sel4(s00, s01, s02, s03, q ^ 2);
        const float go0 = sel4(s00, s01, s02, s03, q ^ 3);
        const float gi1 = sel4(s10, s11, s12, s13, q);
        const float gf1 = sel4(s10, s11, s12, s13, q ^ 1);
        const float gg1 = sel4(s10, s11, s12, s13, q ^ 2);
        const float go1 = sel4(s10, s11, s12, s13, q ^ 3);

        const float cn0 = fsigm(gf0) * c0 + fsigm(gi0) * ftanh(gg0);
        const float hn0 = fsigm(go0) * ftanh(cn0);
        const float cn1 = fsigm(gf1) * c1 + fsigm(gi1) * ftanh(gg1);
        const float hn1 = fsigm(go1) * ftanh(cn1);
        c0 = cn0; c1 = cn1;

        // pack 4 units (lanes a=0..3 of this gate group) into one u64 on lane a==0
        unsigned int x0 = f2bf(hn0), x1 = f2bf(hn1);
        const unsigned int p0 = x0 | ((unsigned int)__shfl_xor((int)x0, 4, 64) << 16);
        const unsigned int p1 = x1 | ((unsigned int)__shfl_xor((int)x1, 4, 64) << 16);
        const u64 w0 = (u64)p0 | ((u64)(unsigned int)__shfl_xor((int)p0, 8, 64) << 32);
        const u64 w1 = (u64)p1 | ((u64)(unsigned int)__shfl_xor((int)p1, 8, 64) << 32);
        if (a == 0) {   // lanes lr==q: batches lk*4+q, units 4w..4w+3
            const int b0 = lk * 4 + q;
            const int ub = p * UPB + 4 * w;   // global unit base (8B aligned in bf16)
            *(u64*)(Hsb + ((size_t)b0 * TT + t) * HH + ub) = w0;
            *(u64*)(Hsb + ((size_t)(b0 + 16) * TT + t) * HH + ub) = w1;
            const size_t o0 = (size_t)b0 * HH + ub, o1 = (size_t)(b0 + 16) * HH + ub;
            const size_t d_s = (size_t)(t & 3) * BB * HH;
            const size_t p_s = (size_t)((t + 2) & 3) * BB * HH;
            __hip_atomic_store((u64*)(hb + d_s + o0), w0, __ATOMIC_RELAXED, __HIP_MEMORY_SCOPE_AGENT);
            __hip_atomic_store((u64*)(hb + d_s + o1), w1, __ATOMIC_RELAXED, __HIP_MEMORY_SCOPE_AGENT);
            __hip_atomic_store((u64*)(hb + p_s + o0), POISON, __ATOMIC_RELAXED, __HIP_MEMORY_SCOPE_AGENT);
            __hip_atomic_store((u64*)(hb + p_s + o1), POISON, __ATOMIC_RELAXED, __HIP_MEMORY_SCOPE_AGENT);
        }
        // NOTE: no second barrier. staging(t+1) writes Hl[(t+1)&1] != Hl[t&1] read by
        // MFMA(t) (double buffer), and staging(t+2)'s reuse of Hl[t&1] is ordered after
        // bar0(t+1), by which point every thread's MFMA(t) reads have completed.
    }
}

// ---------------- Stage D: MFMA bf16 GEMM: out[m][v] = Hsb[m,:] . Woutb[v,:] + bout[v] ----------------
__global__ __launch_bounds__(256, 2) void stage_logits_mfma(const unsigned short* __restrict__ A,
                                                            const unsigned short* __restrict__ Bm,
                                                            const float* __restrict__ bout,
                                                            float* __restrict__ out) {
    __shared__ unsigned short As[128][40];
    __shared__ unsigned short Bs[128][40];
    const int tid = threadIdx.x;
    const int m0 = blockIdx.y * 128;
    const int n0 = blockIdx.x * 128;
    const int w = tid >> 6, l = tid & 63;
    const int wr = w >> 1, wc = w & 1;
    const int lr = l & 15, lk = l >> 4;

    f32x4 acc[4][4] = {};
    for (int k0 = 0; k0 < HH; k0 += 32) {
#pragma unroll
        for (int i = 0; i < 2; ++i) {
            const int uidx = tid + 256 * i;
            const int rr = uidx >> 2, ss = uidx & 3;
            *(uint4*)&As[rr][ss * 8] = *(const uint4*)(A + (size_t)(m0 + rr) * HH + k0 + ss * 8);
            *(uint4*)&Bs[rr][ss * 8] = *(const uint4*)(Bm + (size_t)(n0 + rr) * HH + k0 + ss * 8);
        }
        __syncthreads();
        bf16x8v af[4], bfr[4];
#pragma unroll
        for (int f = 0; f < 4; ++f) {
            af[f]  = *(const bf16x8v*)&As[wr * 64 + f * 16 + lr][lk * 8];
            bfr[f] = *(const bf16x8v*)&Bs[wc * 64 + f * 16 + lr][lk * 8];
        }
#pragma unroll
        for (int fm = 0; fm < 4; ++fm)
#pragma unroll
            for (int fn = 0; fn < 4; ++fn)
                acc[fm][fn] = __builtin_amdgcn_mfma_f32_16x16x32_bf16(af[fm], bfr[fn], acc[fm][fn], 0, 0, 0);
        __syncthreads();
    }
#pragma unroll
    for (int fn = 0; fn < 4; ++fn) {
        const int n = n0 + wc * 64 + fn * 16 + lr;
        const float bv = bout[n];
#pragma unroll
        for (int fm = 0; fm < 4; ++fm) {
            const int mbase = m0 + wr * 64 + fm * 16 + lk * 4;
#pragma unroll
            for (int rg = 0; rg < 4; ++rg)
                out[(size_t)(mbase + rg) * VV + n] = acc[fm][fn][rg] + bv;
        }
    }
}

// ---------------- Stage E: in-place log_softmax over V per row ----------------
__global__ __launch_bounds__(256) void stage_lsm(float* __restrict__ out) {
    __shared__ float buf[VV];
    __shared__ float red[16];
    const size_t m = blockIdx.x;
    float4* row4 = (float4*)(out + m * VV);
    float4* buf4 = (float4*)buf;
    const int tid = threadIdx.x;

    float mx = -INFINITY;
    for (int k4 = tid; k4 < VV / 4; k4 += 256) {
        const float4 v = row4[k4];
        buf4[k4] = v;
        mx = fmaxf(mx, fmaxf(fmaxf(v.x, v.y), fmaxf(v.z, v.w)));
    }
#pragma unroll
    for (int off = 32; off > 0; off >>= 1) mx = fmaxf(mx, __shfl_down(mx, off, 64));
    if ((tid & 63) == 0) red[tid >> 6] = mx;
    __syncthreads();
    if (tid == 0) {
        float m2 = red[0];
        for (int i = 1; i < 4; ++i) m2 = fmaxf(m2, red[i]);
        red[0] = m2;
    }
    __syncthreads();
    mx = red[0];

    float s = 0.f;
    for (int k4 = tid; k4 < VV / 4; k4 += 256) {
        const float4 v = buf4[k4];
        s += __expf(v.x - mx) + __expf(v.y - mx) + __expf(v.z - mx) + __expf(v.w - mx);
    }
#pragma unroll
    for (int off = 32; off > 0; off >>= 1) s += __shfl_down(s, off, 64);
    if ((tid & 63) == 0) red[8 + (tid >> 6)] = s;
    __syncthreads();
    if (tid == 0) {
        float s2 = 0.f;
        for (int i = 0; i < 4; ++i) s2 += red[8 + i];
        red[8] = logf(s2);
    }
    __syncthreads();
    const float lse = mx + red[8];
    for (int k4 = tid; k4 < VV / 4; k4 += 256) {
        float4 v = buf4[k4];
        v.x -= lse; v.y -= lse; v.z -= lse; v.w -= lse;
        row4[k4] = v;
    }
}

extern "C" void kernel_launch(void* const* d_in, const int* in_sizes, int n_in,
                              void* d_out, int out_size, void* d_ws, size_t ws_size,
                              hipStream_t stream) {
    const float* ac   = (const float*)d_in[0];
    const int*   tok  = (const int*)d_in[1];
    const float* emb  = (const float*)d_in[2];
    const float* Win  = (const float*)d_in[3];
    const float* bin  = (const float*)d_in[4];
    const float* Wih  = (const float*)d_in[5];
    const float* Whh  = (const float*)d_in[6];
    const float* bih  = (const float*)d_in[7];
    const float* bhh  = (const float*)d_in[8];
    const float* Wout = (const float*)d_in[9];
    const float* bout = (const float*)d_in[10];
    float* out = (float*)d_out;

    float* X  = (float*)d_ws;                                   // [T*B,H] fp32, 21 MB
    float* Gp = X + (size_t)TT * BB * HH;                       // [T][8][160][32], 84 MB
    unsigned short* Hsb   = (unsigned short*)(Gp + (size_t)TT * BB * G4);  // [B][T][H] bf16
    unsigned short* Woutb = Hsb + (size_t)TT * BB * HH;         // [V][H] bf16
    unsigned short* Whhp  = Woutb + (size_t)VV * HH;            // [8][10][10][64][8] bf16, 800 KB
    unsigned short* hb    = Whhp + (size_t)NBLK * 10 * 10 * 64 * 8;  // [4][BB][HH] bf16, 80 KB

    stage_x<<<dim3(TT * BB / 8), dim3(320), 0, stream>>>(ac, tok, emb, Win, bin, X);
    stage_gin<<<dim3(TT * BB / 8), dim3(256), 0, stream>>>(X, Wih, bih, bhh, Gp);
    wcvt<<<dim3((VV * HH / 4 + 255) / 256), dim3(256), 0, stream>>>(Wout, Woutb, VV * HH / 4);
    wcvt_whh<<<dim3((NBLK * 10 * 10 * 64 + 255) / 256), dim3(256), 0, stream>>>(Whh, Whhp);
    // poison the quad-buffered h exchange buffer (0x7F bytes => bf16 0x7F7F)
    hipMemsetAsync(hb, 0x7F, (size_t)4 * BB * HH * sizeof(unsigned short), stream);
    stage_rec<<<dim3(NBLK), dim3(RTHR), 0, stream>>>(Gp, Whhp, Hsb, hb);
    stage_logits_mfma<<<dim3(VV / 128, TT * BB / 128), dim3(256), 0, stream>>>(Hsb, Woutb, bout, out);
    stage_lsm<<<dim3(TT * BB), dim3(256), 0, stream>>>(out);
}

// Round 17
// 3290.882 us; speedup vs baseline: 1.4501x; 1.4501x over previous
//
#include <hip/hip_runtime.h>
#include <hip/hip_bf16.h>

// Problem constants
#define BB 32     // batch
#define TT 512    // time
#define AA 512    // acoustic dim
#define EE 256    // emb dim
#define HH 320    // hidden
#define VV 8192   // vocab
#define KIN 768   // A+E
#define G4 1280   // 4*H

#define NBLK 8    // recurrence blocks (one sync group)
#define UPB 40    // hidden units per block
#define RTHR 640  // threads (10 waves)
#define GLP 161   // gates LDS row pad (161 % 32 == 1 => conflict-free)

#define POISON 0x7F7F7F7F7F7F7F7FULL   // 4x bf16 0x7F7F — unreachable for h in [-1,1]

typedef __bf16 bf16x8v __attribute__((ext_vector_type(8)));
typedef float f32x4 __attribute__((ext_vector_type(4)));
typedef unsigned long long u64;

__device__ __forceinline__ float fsigm(float x) { return 1.f / (1.f + __expf(-x)); }
__device__ __forceinline__ float ftanh(float x) { return 2.f / (1.f + __expf(-2.f * x)) - 1.f; }
__device__ __forceinline__ unsigned short f2bf(float f) {
    __hip_bfloat16 h = __float2bfloat16(f);
    return *(unsigned short*)&h;
}

// ---------------- Wx fp32 -> bf16 (generic row-major converter) ----------------
__global__ __launch_bounds__(256) void wcvt(const float* __restrict__ src,
                                            unsigned short* __restrict__ dst, int n4) {
    const int i = blockIdx.x * 256 + threadIdx.x;
    if (i < n4) {
        const float4 v = ((const float4*)src)[i];
        ushort4 o;
        o.x = f2bf(v.x); o.y = f2bf(v.y); o.z = f2bf(v.z); o.w = f2bf(v.w);
        ((ushort4*)dst)[i] = o;
    }
}

// ---------------- Stage A (MFMA): Xb[r=t*32+b][n] = bf16(tanh(concat(ac,emb) . Win[n,:] + bin[n])) ----------------
// 128x64 tile, K=768. A staged fp32->bf16 on the fly (no concat intermediate).
__global__ __launch_bounds__(256, 2) void stage_x_mfma(const float* __restrict__ ac,
                                                       const int* __restrict__ tok,
                                                       const float* __restrict__ emb,
                                                       const unsigned short* __restrict__ Winb,
                                                       const float* __restrict__ bin,
                                                       unsigned short* __restrict__ Xb) {
    __shared__ unsigned short As[128][40];
    __shared__ unsigned short Bs[64][40];
    const int tid = threadIdx.x;
    const int m0 = blockIdx.y * 128;
    const int n0 = blockIdx.x * 64;
    const int w = tid >> 6, l = tid & 63;
    const int wr = w >> 1, wc = w & 1;
    const int lr = l & 15, lk = l >> 4;

    f32x4 acc[4][2] = {};
    for (int k0 = 0; k0 < KIN; k0 += 32) {
        // stage A: 128 rows x 32 cols; thread -> (row tid>>1, 16-col half (tid&1))
        {
            const int rr = tid >> 1;
            const int c0 = (tid & 1) * 16;
            const int m = m0 + rr;
            const int t = m >> 5, b = m & 31;
            const int k = k0 + c0;
            float tmp[16];
            if (k < AA) {
                const float4* s = (const float4*)(ac + ((size_t)b * TT + t) * AA + k);
#pragma unroll
                for (int e = 0; e < 4; ++e) *(float4*)&tmp[4 * e] = s[e];
            } else {
                const int tk = tok[b * TT + t];
                if (tk == 0) {
#pragma unroll
                    for (int e = 0; e < 16; ++e) tmp[e] = 0.f;
                } else {
                    const float4* s = (const float4*)(emb + (size_t)tk * EE + (k - AA));
#pragma unroll
                    for (int e = 0; e < 4; ++e) *(float4*)&tmp[4 * e] = s[e];
                }
            }
            unsigned short o[16];
#pragma unroll
            for (int e = 0; e < 16; ++e) o[e] = f2bf(tmp[e]);
            *(uint4*)&As[rr][c0] = *(const uint4*)&o[0];
            *(uint4*)&As[rr][c0 + 8] = *(const uint4*)&o[8];
        }
        // stage B: 64 rows x 32 cols from Winb (row-major 768)
        {
            const int rr = tid >> 2, ss = tid & 3;
            *(uint4*)&Bs[rr][ss * 8] = *(const uint4*)(Winb + (size_t)(n0 + rr) * KIN + k0 + ss * 8);
        }
        __syncthreads();
        bf16x8v af[4], bfv[2];
#pragma unroll
        for (int f = 0; f < 4; ++f) af[f] = *(const bf16x8v*)&As[wr * 64 + f * 16 + lr][lk * 8];
#pragma unroll
        for (int g = 0; g < 2; ++g) bfv[g] = *(const bf16x8v*)&Bs[wc * 32 + g * 16 + lr][lk * 8];
#pragma unroll
        for (int f = 0; f < 4; ++f)
#pragma unroll
            for (int g = 0; g < 2; ++g)
                acc[f][g] = __builtin_amdgcn_mfma_f32_16x16x32_bf16(af[f], bfv[g], acc[f][g], 0, 0, 0);
        __syncthreads();
    }
#pragma unroll
    for (int g = 0; g < 2; ++g) {
        const int n = n0 + wc * 32 + g * 16 + lr;
        const float bv = bin[n];
#pragma unroll
        for (int f = 0; f < 4; ++f) {
            const int mbase = m0 + wr * 64 + f * 16 + lk * 4;
#pragma unroll
            for (int rg = 0; rg < 4; ++rg)
                Xb[(size_t)(mbase + rg) * HH + n] = f2bf(tanhf(acc[f][g][rg] + bv));
        }
    }
}

// ---------------- Stage B (MFMA): Gp[t][p][q][ug][b][4] = Xb . Wih^T + bih + bhh ----------------
// 128x128 tile, K=320; epilogue scatters into the rec-friendly Gp layout.
__global__ __launch_bounds__(256, 2) void stage_gin_mfma(const unsigned short* __restrict__ A,
                                                         const unsigned short* __restrict__ Bm,
                                                         const float* __restrict__ bih,
                                                         const float* __restrict__ bhh,
                                                         float* __restrict__ Gp) {
    __shared__ unsigned short As[128][40];
    __shared__ unsigned short Bs[128][40];
    const int tid = threadIdx.x;
    const int m0 = blockIdx.y * 128;
    const int n0 = blockIdx.x * 128;
    const int w = tid >> 6, l = tid & 63;
    const int wr = w >> 1, wc = w & 1;
    const int lr = l & 15, lk = l >> 4;

    f32x4 acc[4][4] = {};
    for (int k0 = 0; k0 < HH; k0 += 32) {
#pragma unroll
        for (int i = 0; i < 2; ++i) {
            const int uidx = tid + 256 * i;
            const int rr = uidx >> 2, ss = uidx & 3;
            *(uint4*)&As[rr][ss * 8] = *(const uint4*)(A + (size_t)(m0 + rr) * HH + k0 + ss * 8);
            *(uint4*)&Bs[rr][ss * 8] = *(const uint4*)(Bm + (size_t)(n0 + rr) * HH + k0 + ss * 8);
        }
        __syncthreads();
        bf16x8v af[4], bfv[4];
#pragma unroll
        for (int f = 0; f < 4; ++f) {
            af[f]  = *(const bf16x8v*)&As[wr * 64 + f * 16 + lr][lk * 8];
            bfv[f] = *(const bf16x8v*)&Bs[wc * 64 + f * 16 + lr][lk * 8];
        }
#pragma unroll
        for (int fm = 0; fm < 4; ++fm)
#pragma unroll
            for (int fn = 0; fn < 4; ++fn)
                acc[fm][fn] = __builtin_amdgcn_mfma_f32_16x16x32_bf16(af[fm], bfv[fn], acc[fm][fn], 0, 0, 0);
        __syncthreads();
    }
#pragma unroll
    for (int fn = 0; fn < 4; ++fn) {
        const int j = n0 + wc * 64 + fn * 16 + lr;   // gate row 0..1279
        const float bias = bih[j] + bhh[j];
        const int q = j / HH;
        const int hi = j - q * HH;
        const int pp = hi / UPB;
        const int uu = hi - pp * UPB;
        const int ug = uu >> 2, u4 = uu & 3;
#pragma unroll
        for (int fm = 0; fm < 4; ++fm) {
            const int mbase = m0 + wr * 64 + fm * 16 + lk * 4;
#pragma unroll
            for (int rg = 0; rg < 4; ++rg) {
                const int m = mbase + rg;
                const int t = m >> 5, b = m & 31;
                Gp[((((size_t)t * NBLK + pp) * 4 + q) * 10 + ug) * 128 + b * 4 + u4] =
                    acc[fm][fn][rg] + bias;
            }
        }
    }
}

// ---------------- Whh -> bf16, per-slice frag layout [p(8)][tile(10)][kc(10)][lane(64)][8] ----------------
__global__ __launch_bounds__(256) void wcvt_whh(const float* __restrict__ Whh,
                                                unsigned short* __restrict__ dst) {
    const int i = blockIdx.x * 256 + threadIdx.x;   // 0 .. 8*10*10*64-1
    if (i >= NBLK * 10 * 10 * 64) return;
    const int l = i & 63;
    const int kc = (i >> 6) % 10;
    const int tw = (i / 640) % 10;
    const int p = i / 6400;
    const int sr = tw * 16 + (l & 15);
    const int grow = (sr / UPB) * HH + p * UPB + (sr % UPB);
    const int k0 = kc * 32 + (l >> 4) * 8;
    const float* s = Whh + (size_t)grow * HH + k0;
    const float4 v0 = *(const float4*)s;
    const float4 v1 = *(const float4*)(s + 4);
    unsigned short tmp[8] = { f2bf(v0.x), f2bf(v0.y), f2bf(v0.z), f2bf(v0.w),
                              f2bf(v1.x), f2bf(v1.y), f2bf(v1.z), f2bf(v1.w) };
    *(uint4*)(dst + (size_t)i * 8) = *(const uint4*)tmp;
}

// ---------------- Stage C: batched MFMA recurrence, 8 blocks, cooperative poison-poll ----------------
// (r15-proven version, byte-identical logic: 2.77 ms measured)
__global__ __launch_bounds__(RTHR) void stage_rec(const float* __restrict__ Gp,
                                                  const unsigned short* __restrict__ Whhp,
                                                  unsigned short* __restrict__ Hsb,
                                                  unsigned short* __restrict__ hb) { // [4][BB][HH]
    const int p = blockIdx.x;             // 0..7
    const int tid = threadIdx.x;
    const int l = tid & 63, w = tid >> 6; // wave = n-tile 0..9
    const int lr = l & 15, lk = l >> 4;

    __shared__ unsigned short Hl[32][328]; // 21.0 KB (pad 328: 2-way-conflict-free reads)
    __shared__ float Gl[BB * GLP];         // 20.6 KB

    // ---- B fragments: 10 per lane (one n-tile per wave), pre-converted bf16 ----
    bf16x8v bfr[10];
#pragma unroll
    for (int kc = 0; kc < 10; ++kc)
        bfr[kc] = *(const bf16x8v*)(Whhp + ((size_t)((p * 10 + w) * 10 + kc) * 64 + l) * 8);

    const int mc = tid & 31;              // batch for cell update
    const int gidx = tid >> 5;            // unit-group; cell phase uses gidx<10
    const int uc0 = gidx * 4;             // 4 adjacent units
    float c0 = 0.f, c1 = 0.f, c2 = 0.f, c3 = 0.f;

    // staging ownership: thread owns 32B = 16 units of batch sm at k-offset sk
    const int sm = tid / 20;              // 0..31
    const int sk = (tid - sm * 20) * 16;  // 0,16,...,304

    for (int t = 0; t < TT; ++t) {
        // gate-input prefetch: one float4 per q (coalesced across mc)
        float4 g[4];
        if (gidx < 10) {
            const size_t gbase = ((size_t)t * NBLK + p) * 4;
#pragma unroll
            for (int q = 0; q < 4; ++q)
                g[q] = ((const float4*)Gp)[(gbase + q) * 320 + (size_t)gidx * 32 + mc];
        }
        if (t > 0) {
            // ---- cooperative staging: poll own 32B chunk of slot (t-1)%4 ----
            const int slot = (t - 1) & 3;
            const u64* src = (const u64*)(hb + ((size_t)slot * BB + sm) * HH + sk);
            u64 v0, v1, v2, v3;
            for (;;) {
                v0 = __hip_atomic_load(src + 0, __ATOMIC_RELAXED, __HIP_MEMORY_SCOPE_AGENT);
                v1 = __hip_atomic_load(src + 1, __ATOMIC_RELAXED, __HIP_MEMORY_SCOPE_AGENT);
                v2 = __hip_atomic_load(src + 2, __ATOMIC_RELAXED, __HIP_MEMORY_SCOPE_AGENT);
                v3 = __hip_atomic_load(src + 3, __ATOMIC_RELAXED, __HIP_MEMORY_SCOPE_AGENT);
                if (v0 != POISON && v1 != POISON && v2 != POISON && v3 != POISON) break;
            }
            u64* d = (u64*)&Hl[sm][sk];
            d[0] = v0; d[1] = v1; d[2] = v2; d[3] = v3;
        }
        __syncthreads();   // bar0: Hl staged (also gates Gl WAR from previous step's cell)
        if (t > 0) {
            f32x4 acc0 = {}, acc1 = {};
#pragma unroll
            for (int kc = 0; kc < 10; ++kc) {
                const bf16x8v av0 = *(const bf16x8v*)&Hl[lr][kc * 32 + lk * 8];
                const bf16x8v av1 = *(const bf16x8v*)&Hl[16 + lr][kc * 32 + lk * 8];
                acc0 = __builtin_amdgcn_mfma_f32_16x16x32_bf16(av0, bfr[kc], acc0, 0, 0, 0);
                acc1 = __builtin_amdgcn_mfma_f32_16x16x32_bf16(av1, bfr[kc], acc1, 0, 0, 0);
            }
            // C/D: row=(lane>>4)*4+reg -> batch; col=lane&15 -> gate-row in n-tile w
#pragma unroll
            for (int rg = 0; rg < 4; ++rg) {
                Gl[(lk * 4 + rg) * GLP + w * 16 + lr] = acc0[rg];
                Gl[(16 + lk * 4 + rg) * GLP + w * 16 + lr] = acc1[rg];
            }
        }
        __syncthreads();   // bar1: Gl ready

        if (gidx < 10) {
            float a[4][4];
#pragma unroll
            for (int q = 0; q < 4; ++q) {
                const float* gl = &Gl[mc * GLP + q * UPB + uc0];
                a[q][0] = g[q].x + (t > 0 ? gl[0] : 0.f);
                a[q][1] = g[q].y + (t > 0 ? gl[1] : 0.f);
                a[q][2] = g[q].z + (t > 0 ? gl[2] : 0.f);
                a[q][3] = g[q].w + (t > 0 ? gl[3] : 0.f);
            }
            const float n0 = fsigm(a[1][0]) * c0 + fsigm(a[0][0]) * ftanh(a[2][0]);
            const float n1 = fsigm(a[1][1]) * c1 + fsigm(a[0][1]) * ftanh(a[2][1]);
            const float n2 = fsigm(a[1][2]) * c2 + fsigm(a[0][2]) * ftanh(a[2][2]);
            const float n3 = fsigm(a[1][3]) * c3 + fsigm(a[0][3]) * ftanh(a[2][3]);
            const float h0 = fsigm(a[3][0]) * ftanh(n0);
            const float h1 = fsigm(a[3][1]) * ftanh(n1);
            const float h2 = fsigm(a[3][2]) * ftanh(n2);
            const float h3 = fsigm(a[3][3]) * ftanh(n3);
            c0 = n0; c1 = n1; c2 = n2; c3 = n3;
            const u64 hpk =
                (u64)f2bf(h0) | ((u64)f2bf(h1) << 16) |
                ((u64)f2bf(h2) << 32) | ((u64)f2bf(h3) << 48);
            *(u64*)(Hsb + ((size_t)mc * TT + t) * HH + p * UPB + uc0) = hpk;
            const size_t off = (size_t)mc * HH + p * UPB + uc0;   // within one hb slot
            // publish data for step t; poison the slot cell(t+2) will fill
            __hip_atomic_store((u64*)(hb + ((size_t)(t & 3) * BB * HH) + off), hpk,
                               __ATOMIC_RELAXED, __HIP_MEMORY_SCOPE_AGENT);
            __hip_atomic_store((u64*)(hb + ((size_t)((t + 2) & 3) * BB * HH) + off), POISON,
                               __ATOMIC_RELAXED, __HIP_MEMORY_SCOPE_AGENT);
        }
        // no loop-end barrier: Hl/Gl WARs are gated by bar0 of the next iteration
    }
}

// ---------------- Stage D: MFMA bf16 GEMM: out[m][v] = Hsb[m,:] . Woutb[v,:] + bout[v] ----------------
__global__ __launch_bounds__(256, 2) void stage_logits_mfma(const unsigned short* __restrict__ A,
                                                            const unsigned short* __restrict__ Bm,
                                                            const float* __restrict__ bout,
                                                            float* __restrict__ out) {
    __shared__ unsigned short As[128][40];
    __shared__ unsigned short Bs[128][40];
    const int tid = threadIdx.x;
    const int m0 = blockIdx.y * 128;
    const int n0 = blockIdx.x * 128;
    const int w = tid >> 6, l = tid & 63;
    const int wr = w >> 1, wc = w & 1;
    const int lr = l & 15, lk = l >> 4;

    f32x4 acc[4][4] = {};
    for (int k0 = 0; k0 < HH; k0 += 32) {
#pragma unroll
        for (int i = 0; i < 2; ++i) {
            const int uidx = tid + 256 * i;
            const int rr = uidx >> 2, ss = uidx & 3;
            *(uint4*)&As[rr][ss * 8] = *(const uint4*)(A + (size_t)(m0 + rr) * HH + k0 + ss * 8);
            *(uint4*)&Bs[rr][ss * 8] = *(const uint4*)(Bm + (size_t)(n0 + rr) * HH + k0 + ss * 8);
        }
        __syncthreads();
        bf16x8v af[4], bfv[4];
#pragma unroll
        for (int f = 0; f < 4; ++f) {
            af[f]  = *(const bf16x8v*)&As[wr * 64 + f * 16 + lr][lk * 8];
            bfv[f] = *(const bf16x8v*)&Bs[wc * 64 + f * 16 + lr][lk * 8];
        }
#pragma unroll
        for (int fm = 0; fm < 4; ++fm)
#pragma unroll
            for (int fn = 0; fn < 4; ++fn)
                acc[fm][fn] = __builtin_amdgcn_mfma_f32_16x16x32_bf16(af[fm], bfv[fn], acc[fm][fn], 0, 0, 0);
        __syncthreads();
    }
#pragma unroll
    for (int fn = 0; fn < 4; ++fn) {
        const int n = n0 + wc * 64 + fn * 16 + lr;
        const float bv = bout[n];
#pragma unroll
        for (int fm = 0; fm < 4; ++fm) {
            const int mbase = m0 + wr * 64 + fm * 16 + lk * 4;
#pragma unroll
            for (int rg = 0; rg < 4; ++rg)
                out[(size_t)(mbase + rg) * VV + n] = acc[fm][fn][rg] + bv;
        }
    }
}

// ---------------- Stage E: in-place log_softmax over V per row ----------------
__global__ __launch_bounds__(256) void stage_lsm(float* __restrict__ out) {
    __shared__ float buf[VV];
    __shared__ float red[16];
    const size_t m = blockIdx.x;
    float4* row4 = (float4*)(out + m * VV);
    float4* buf4 = (float4*)buf;
    const int tid = threadIdx.x;

    float mx = -INFINITY;
    for (int k4 = tid; k4 < VV / 4; k4 += 256) {
        const float4 v = row4[k4];
        buf4[k4] = v;
        mx = fmaxf(mx, fmaxf(fmaxf(v.x, v.y), fmaxf(v.z, v.w)));
    }
#pragma unroll
    for (int off = 32; off > 0; off >>= 1) mx = fmaxf(mx, __shfl_down(mx, off, 64));
    if ((tid & 63) == 0) red[tid >> 6] = mx;
    __syncthreads();
    if (tid == 0) {
        float m2 = red[0];
        for (int i = 1; i < 4; ++i) m2 = fmaxf(m2, red[i]);
        red[0] = m2;
    }
    __syncthreads();
    mx = red[0];

    float s = 0.f;
    for (int k4 = tid; k4 < VV / 4; k4 += 256) {
        const float4 v = buf4[k4];
        s += __expf(v.x - mx) + __expf(v.y - mx) + __expf(v.z - mx) + __expf(v.w - mx);
    }
#pragma unroll
    for (int off = 32; off > 0; off >>= 1) s += __shfl_down(s, off, 64);
    if ((tid & 63) == 0) red[8 + (tid >> 6)] = s;
    __syncthreads();
    if (tid == 0) {
        float s2 = 0.f;
        for (int i = 0; i < 4; ++i) s2 += red[8 + i];
        red[8] = logf(s2);
    }
    __syncthreads();
    const float lse = mx + red[8];
    for (int k4 = tid; k4 < VV / 4; k4 += 256) {
        float4 v = buf4[k4];
        v.x -= lse; v.y -= lse; v.z -= lse; v.w -= lse;
        row4[k4] = v;
    }
}

extern "C" void kernel_launch(void* const* d_in, const int* in_sizes, int n_in,
                              void* d_out, int out_size, void* d_ws, size_t ws_size,
                              hipStream_t stream) {
    const float* ac   = (const float*)d_in[0];
    const int*   tok  = (const int*)d_in[1];
    const float* emb  = (const float*)d_in[2];
    const float* Win  = (const float*)d_in[3];
    const float* bin  = (const float*)d_in[4];
    const float* Wih  = (const float*)d_in[5];
    const float* Whh  = (const float*)d_in[6];
    const float* bih  = (const float*)d_in[7];
    const float* bhh  = (const float*)d_in[8];
    const float* Wout = (const float*)d_in[9];
    const float* bout = (const float*)d_in[10];
    float* out = (float*)d_out;

    float* Gp = (float*)d_ws;                                   // [T][8][4][10][32][4], 84 MB
    unsigned short* Xb    = (unsigned short*)(Gp + (size_t)TT * BB * G4);  // [T*B][H] bf16, 10.5 MB
    unsigned short* Hsb   = Xb + (size_t)TT * BB * HH;          // [B][T][H] bf16, 10.5 MB
    unsigned short* Woutb = Hsb + (size_t)TT * BB * HH;         // [V][H] bf16, 5.2 MB
    unsigned short* Winb  = Woutb + (size_t)VV * HH;            // [H][KIN] bf16, 0.5 MB
    unsigned short* Wihb  = Winb + (size_t)HH * KIN;            // [4H][H] bf16, 0.8 MB
    unsigned short* Whhp  = Wihb + (size_t)G4 * HH;             // [8][10][10][64][8] bf16, 0.8 MB
    unsigned short* hb    = Whhp + (size_t)NBLK * 10 * 10 * 64 * 8;  // [4][BB][HH] bf16, 80 KB

    wcvt<<<dim3((HH * KIN / 4 + 255) / 256), dim3(256), 0, stream>>>(Win, Winb, HH * KIN / 4);
    wcvt<<<dim3((G4 * HH / 4 + 255) / 256), dim3(256), 0, stream>>>(Wih, Wihb, G4 * HH / 4);
    wcvt<<<dim3((VV * HH / 4 + 255) / 256), dim3(256), 0, stream>>>(Wout, Woutb, VV * HH / 4);
    wcvt_whh<<<dim3((NBLK * 10 * 10 * 64 + 255) / 256), dim3(256), 0, stream>>>(Whh, Whhp);
    stage_x_mfma<<<dim3(HH / 64, TT * BB / 128), dim3(256), 0, stream>>>(ac, tok, emb, Winb, bin, Xb);
    stage_gin_mfma<<<dim3(G4 / 128, TT * BB / 128), dim3(256), 0, stream>>>(Xb, Wihb, bih, bhh, Gp);
    // poison the quad-buffered h exchange buffer (0x7F bytes => bf16 0x7F7F)
    hipMemsetAsync(hb, 0x7F, (size_t)4 * BB * HH * sizeof(unsigned short), stream);
    stage_rec<<<dim3(NBLK), dim3(RTHR), 0, stream>>>(Gp, Whhp, Hsb, hb);
    stage_logits_mfma<<<dim3(VV / 128, TT * BB / 128), dim3(256), 0, stream>>>(Hsb, Woutb, bout, out);
    stage_lsm<<<dim3(TT * BB), dim3(256), 0, stream>>>(out);
}